// Round 1
// baseline (80.083 us; speedup 1.0000x reference)
//
#include <hip/hip_runtime.h>

// Problem constants (match reference)
#define B_ 16
#define F_ 256
#define N_ 16384
#define L_ 4096
#define K_ 9

// ---------------------------------------------------------------------------
// Pre-pass: fold mask into index and transpose to (K, L) as uint16.
// masked (mask==0) -> sentinel index N_ (LDS row slot N_ holds 0.0f).
// ---------------------------------------------------------------------------
__global__ __launch_bounds__(256) void prep_comb_kernel(
    const int* __restrict__ idx, const float* __restrict__ mask,
    unsigned short* __restrict__ comb) {
  int t = blockIdx.x * blockDim.x + threadIdx.x;  // over L_*K_
  if (t >= L_ * K_) return;
  int l = t / K_;
  int k = t - l * K_;
  int id = idx[t];
  float m = mask[t];
  comb[k * L_ + l] = (m != 0.0f) ? (unsigned short)id : (unsigned short)N_;
}

// ---------------------------------------------------------------------------
// Main kernel: one block per (b,f) row. Stage the 64 KiB row in LDS
// (plus a 0.0f sentinel at slot N_), then 9 LDS gathers + fmax per output.
// ---------------------------------------------------------------------------
__global__ __launch_bounds__(256) void pool_kernel(
    const float* __restrict__ img, const unsigned short* __restrict__ comb,
    float* __restrict__ out) {
  __shared__ __align__(16) float row[N_ + 4];  // sentinel at row[N_]
  const int bf = blockIdx.x;  // 0 .. B_*F_-1
  const int tid = threadIdx.x;

  // Stage row: 16384 floats = 4096 float4; 256 threads -> 16 float4 each.
  const float4* src4 = (const float4*)(img + (size_t)bf * N_);
  float4* row4 = (float4*)row;
#pragma unroll
  for (int i = 0; i < 16; ++i) {
    int j = i * 256 + tid;
    row4[j] = src4[j];
  }
  if (tid == 0) row[N_] = 0.0f;
  __syncthreads();

  float* outp = out + (size_t)bf * L_;
#pragma unroll
  for (int it = 0; it < L_ / 256; ++it) {
    int l = it * 256 + tid;
    float m = -INFINITY;
#pragma unroll
    for (int k = 0; k < K_; ++k) {
      int id = comb[k * L_ + l];  // coalesced ushort load, L2-resident
      m = fmaxf(m, row[id]);      // LDS gather (sentinel -> 0.0f)
    }
    outp[l] = m;  // coalesced
  }
}

// ---------------------------------------------------------------------------
// Fallback (ws too small): read raw indices + mask directly.
// ---------------------------------------------------------------------------
__global__ __launch_bounds__(256) void pool_kernel_direct(
    const float* __restrict__ img, const int* __restrict__ idx,
    const float* __restrict__ mask, float* __restrict__ out) {
  __shared__ __align__(16) float row[N_ + 4];
  const int bf = blockIdx.x;
  const int tid = threadIdx.x;

  const float4* src4 = (const float4*)(img + (size_t)bf * N_);
  float4* row4 = (float4*)row;
#pragma unroll
  for (int i = 0; i < 16; ++i) {
    int j = i * 256 + tid;
    row4[j] = src4[j];
  }
  __syncthreads();

  float* outp = out + (size_t)bf * L_;
  for (int it = 0; it < L_ / 256; ++it) {
    int l = it * 256 + tid;
    float m = -INFINITY;
#pragma unroll
    for (int k = 0; k < K_; ++k) {
      int t = l * K_ + k;
      float v = (mask[t] != 0.0f) ? row[idx[t]] : 0.0f;
      m = fmaxf(m, v);
    }
    outp[l] = m;
  }
}

extern "C" void kernel_launch(void* const* d_in, const int* in_sizes, int n_in,
                              void* d_out, int out_size, void* d_ws, size_t ws_size,
                              hipStream_t stream) {
  const float* img = (const float*)d_in[0];
  const int* idx = (const int*)d_in[1];
  const float* mask = (const float*)d_in[2];
  float* out = (float*)d_out;

  const size_t comb_bytes = (size_t)L_ * K_ * sizeof(unsigned short);
  if (ws_size >= comb_bytes) {
    unsigned short* comb = (unsigned short*)d_ws;
    int total = L_ * K_;
    prep_comb_kernel<<<(total + 255) / 256, 256, 0, stream>>>(idx, mask, comb);
    pool_kernel<<<B_ * F_, 256, 0, stream>>>(img, comb, out);
  } else {
    pool_kernel_direct<<<B_ * F_, 256, 0, stream>>>(img, idx, mask, out);
  }
}